// Round 4
// baseline (305.186 us; speedup 1.0000x reference)
//
#include <hip/hip_runtime.h>
#include <stdint.h>
#include <stddef.h>

// Problem constants
#define BN 16
#define CN 128
#define HN 56
#define WN 56
#define HWN 3136            // H*W
#define FN 9                // K*K deformation taps
#define DN 18               // 2*F offset channels
#define ON 512              // OUT
#define KN 1152             // F*C  (GEMM K)
#define MN 50176            // B*H*W (GEMM M)

typedef __bf16 bf16x8 __attribute__((ext_vector_type(8)));
typedef float f32x4 __attribute__((ext_vector_type(4)));

__device__ __forceinline__ unsigned short f2bf(float f) {
  unsigned int u = __builtin_bit_cast(unsigned int, f);
  u += 0x7fffu + ((u >> 16) & 1u);   // round-to-nearest-even
  return (unsigned short)(u >> 16);
}

__device__ __forceinline__ void gload_lds16(const void* g, void* l) {
  __builtin_amdgcn_global_load_lds(
      (const __attribute__((address_space(1))) unsigned int*)g,
      (__attribute__((address_space(3))) unsigned int*)l, 16, 0, 0);
}

// ---------------- Phase 0a: x fp32 [B,C,HW] -> xt bf16 [B,HW,C] ----------------
__global__ void k_transpose(const float* __restrict__ x, unsigned short* __restrict__ xt) {
  __shared__ float tile[32][33];
  const int b = blockIdx.z;
  const int hw0 = blockIdx.x * 32;   // 3136/32 = 98 exact
  const int c0 = blockIdx.y * 32;    // 128/32 = 4 exact
  const int tx = threadIdx.x & 31;
  const int ty = threadIdx.x >> 5;   // 0..7
  const float* xb = x + (size_t)b * CN * HWN;
  unsigned short* xtb = xt + (size_t)b * HWN * CN;
#pragma unroll
  for (int r = 0; r < 4; ++r)
    tile[ty + r * 8][tx] = xb[(size_t)(c0 + ty + r * 8) * HWN + hw0 + tx];
  __syncthreads();
#pragma unroll
  for (int r = 0; r < 4; ++r)
    xtb[(size_t)(hw0 + ty + r * 8) * CN + c0 + tx] = f2bf(tile[tx][ty + r * 8]);
}

// ---------------- Phase 0b: w_conv fp32 -> bf16 ----------------
__global__ void k_wconv(const float4* __restrict__ w, ushort4* __restrict__ wb) {
  const int i = blockIdx.x * 256 + threadIdx.x;  // 512*1152/4 = 147456 exact
  float4 v = w[i];
  ushort4 o;
  o.x = f2bf(v.x); o.y = f2bf(v.y); o.z = f2bf(v.z); o.w = f2bf(v.w);
  wb[i] = o;
}

// ---------------- Phase 1: per-pixel offset conv -> (ix,iy) per tap ------------
__global__ void k_offsets(const unsigned short* __restrict__ xt, const float* __restrict__ w_off,
                          const float* __restrict__ b_off, float2* __restrict__ ixy) {
  const int m = blockIdx.x * 256 + threadIdx.x;  // 50176 = 196*256 exact
  const int b = m / HWN;
  const int hw = m - b * HWN;
  const int h = hw / WN;
  const int w = hw - h * WN;
  const unsigned short* xp = xt + (size_t)m * CN;
  float acc[DN];
#pragma unroll
  for (int d = 0; d < DN; ++d) acc[d] = b_off[d];
  for (int c = 0; c < CN; c += 8) {
    bf16x8 xv = *(const bf16x8*)(xp + c);
    float xf[8];
#pragma unroll
    for (int q = 0; q < 8; ++q) xf[q] = (float)xv[q];
#pragma unroll
    for (int d = 0; d < DN; ++d) {
      const float* wr = w_off + d * CN + c;  // wave-uniform -> s_load
#pragma unroll
      for (int q = 0; q < 8; ++q) acc[d] += xf[q] * wr[q];
    }
  }
  const float scale = 2.0f / 56.0f;
  const float bx = (2.0f * w + 1.0f) / (float)WN - 1.0f;
  const float by = (2.0f * h + 1.0f) / (float)HN - 1.0f;
#pragma unroll
  for (int f = 0; f < FN; ++f) {
    float gx = bx + acc[2 * f] * scale;
    float gy = by + acc[2 * f + 1] * scale;
    float ixv = ((gx + 1.0f) * (float)WN - 1.0f) * 0.5f;
    float iyv = ((gy + 1.0f) * (float)HN - 1.0f) * 0.5f;
    ixy[(size_t)m * FN + f] = make_float2(ixv, iyv);
  }
}

// ---------------- Phase 2: bilinear sample (bf16 in) -> S bf16 [M, K] ----------
// grid.y carries the tap index f -> no integer division in the kernel.
__global__ void k_sample(const unsigned short* __restrict__ xt, const float2* __restrict__ ixy,
                         unsigned short* __restrict__ S) {
  const int tid = threadIdx.x;
  const int cc = tid & 7;                          // 16-channel chunk
  const int m = blockIdx.x * 32 + (tid >> 3);      // 50176/32 = 1568 exact
  const int f = blockIdx.y;                        // 0..8
  const int b = m / HWN;

  const float2 p = ixy[(size_t)m * FN + f];
  const float ix = p.x, iy = p.y;
  const float x0f = floorf(ix), y0f = floorf(iy);
  const float wx1 = ix - x0f, wy1 = iy - y0f;
  const float wx0 = 1.0f - wx1, wy0 = 1.0f - wy1;
  const int x0 = (int)x0f, y0 = (int)y0f;
  const int x1 = x0 + 1, y1 = y0 + 1;
  const bool vx0 = (x0 >= 0) & (x0 < WN), vx1 = (x1 >= 0) & (x1 < WN);
  const bool vy0 = (y0 >= 0) & (y0 < HN), vy1 = (y1 >= 0) & (y1 < HN);
  const float w00 = wy0 * wx0 * ((vy0 & vx0) ? 1.0f : 0.0f);
  const float w01 = wy0 * wx1 * ((vy0 & vx1) ? 1.0f : 0.0f);
  const float w10 = wy1 * wx0 * ((vy1 & vx0) ? 1.0f : 0.0f);
  const float w11 = wy1 * wx1 * ((vy1 & vx1) ? 1.0f : 0.0f);
  const int x0c = min(max(x0, 0), WN - 1), x1c = min(max(x1, 0), WN - 1);
  const int y0c = min(max(y0, 0), HN - 1), y1c = min(max(y1, 0), HN - 1);

  const unsigned short* bp = xt + (size_t)b * HWN * CN + cc * 16;
  const bf16x8* p00 = (const bf16x8*)(bp + (size_t)(y0c * WN + x0c) * CN);
  const bf16x8* p01 = (const bf16x8*)(bp + (size_t)(y0c * WN + x1c) * CN);
  const bf16x8* p10 = (const bf16x8*)(bp + (size_t)(y1c * WN + x0c) * CN);
  const bf16x8* p11 = (const bf16x8*)(bp + (size_t)(y1c * WN + x1c) * CN);
  bf16x8 a0 = p00[0], a1 = p00[1];
  bf16x8 b0 = p01[0], b1 = p01[1];
  bf16x8 c0 = p10[0], c1 = p10[1];
  bf16x8 d0 = p11[0], d1 = p11[1];

  unsigned short ov[16];
#pragma unroll
  for (int q = 0; q < 8; ++q) {
    float lo = w00 * (float)a0[q] + w01 * (float)b0[q] + w10 * (float)c0[q] + w11 * (float)d0[q];
    float hi = w00 * (float)a1[q] + w01 * (float)b1[q] + w10 * (float)c1[q] + w11 * (float)d1[q];
    ov[q] = f2bf(lo);
    ov[q + 8] = f2bf(hi);
  }
  uint4* dst = (uint4*)(S + (size_t)m * KN + f * CN + cc * 16);
  dst[0] = *(const uint4*)(ov);
  dst[1] = *(const uint4*)(ov + 8);
}

// ---------------- Phase 3: GEMM  out[o,m] = sum_k Wb[o,k]*S[m,k] + bias[o] ------
// 128x128 tile, BK=64, XOR-swizzled LDS, double-buffered pipelined K-loop
// (prefetch next tile via global_load_lds BEFORE compute; 1 barrier/iter),
// single-pass 64KB LDS-staged epilogue.
__global__ __launch_bounds__(256) void k_gemm(const unsigned short* __restrict__ Wb,
                                              const unsigned short* __restrict__ S,
                                              const float* __restrict__ bias,
                                              float* __restrict__ out) {
  __shared__ __align__(16) char smem[65536];
  // buffers: lw[buf] @ buf*16384, ls[buf] @ 32768 + buf*16384  (shorts: 8192 per buf)
  unsigned short* lwB = (unsigned short*)smem;
  unsigned short* lsB = (unsigned short*)(smem + 32768);
  const int tid = threadIdx.x;
  const int wave = tid >> 6;
  const int lane = tid & 63;
  const int quad = lane >> 4;
  const int r16 = lane & 15;
  const int o0 = blockIdx.x * 128;  // out-channel tile (4)
  const int p0 = blockIdx.y * 128;  // pixel tile (392)
  const int wrow = wave >> 1;       // o-dim wave
  const int wcol = wave & 1;        // m-dim wave

  f32x4 acc[4][4];
#pragma unroll
  for (int i = 0; i < 4; ++i)
#pragma unroll
    for (int j = 0; j < 4; ++j) acc[i][j] = (f32x4){0.f, 0.f, 0.f, 0.f};

  // staging: thread covers row row0(+32 per round), swizzled chunk (ch ^ row&7)
  const int row0 = tid >> 3;                              // 0..31
  const int swc = (((tid & 7) ^ (row0 & 7))) * 8;         // swizzled col (shorts)
  const unsigned short* gw = Wb + (size_t)(o0 + row0) * KN + swc;
  const unsigned short* gs = S + (size_t)(p0 + row0) * KN + swc;
  const int ldst = wave * 512;      // wave-uniform LDS base offset (shorts)

  // reader: row = wrow*64+i*16+r16 (row&7 == r16&7), chunk c=quad+h*4 -> c^(r16&7)
  const int rsw = r16 & 7;
  const int ch0 = (quad ^ rsw) * 8;                 // h=0 chunk offset (shorts)
  const int ch1 = ((quad ^ rsw) ^ 4) * 8;           // h=1
  const int awo = (wrow * 64 + r16) * 64;
  const int bso = (wcol * 64 + r16) * 64;

  // prologue: stage kt=0 into buf 0
#pragma unroll
  for (int r = 0; r < 4; ++r) {
    gload_lds16(gw + (size_t)r * 32 * KN, lwB + ldst + r * 2048);
    gload_lds16(gs + (size_t)r * 32 * KN, lsB + ldst + r * 2048);
  }
  gw += 64; gs += 64;
  __syncthreads();

  for (int kt = 0; kt < KN / 64; ++kt) {
    const int cur = (kt & 1) * 8192;
    const int nxt = 8192 - cur;
    if (kt < KN / 64 - 1) {
#pragma unroll
      for (int r = 0; r < 4; ++r) {
        gload_lds16(gw + (size_t)r * 32 * KN, lwB + nxt + ldst + r * 2048);
        gload_lds16(gs + (size_t)r * 32 * KN, lsB + nxt + ldst + r * 2048);
      }
      gw += 64; gs += 64;
    }
    const unsigned short* aw = lwB + cur + awo;
    const unsigned short* bs = lsB + cur + bso;
#pragma unroll
    for (int h = 0; h < 2; ++h) {
      const int ch = h ? ch1 : ch0;
      bf16x8 afr[4], bfr[4];
#pragma unroll
      for (int i = 0; i < 4; ++i) afr[i] = *(const bf16x8*)(aw + i * 16 * 64 + ch);
#pragma unroll
      for (int j = 0; j < 4; ++j) bfr[j] = *(const bf16x8*)(bs + j * 16 * 64 + ch);
#pragma unroll
      for (int i = 0; i < 4; ++i)
#pragma unroll
        for (int j = 0; j < 4; ++j)
          acc[i][j] = __builtin_amdgcn_mfma_f32_16x16x32_bf16(afr[i], bfr[j], acc[i][j], 0, 0, 0);
    }
    __syncthreads();  // readers done with cur; next-tile loads drained (vmcnt 0)
  }

  // Epilogue: stage full 128 o-rows x 128 p-cols fp32 in 64KB smem, write lines.
  // C/D layout: col(m)=r16, row(o)=quad*4+reg.
  float* lout = (float*)smem;
#pragma unroll
  for (int i = 0; i < 4; ++i) {
    const int orow = wrow * 64 + i * 16 + quad * 4;
#pragma unroll
    for (int j = 0; j < 4; ++j) {
      const int col = wcol * 64 + j * 16 + r16;
      lout[(orow + 0) * 128 + col] = acc[i][j][0];
      lout[(orow + 1) * 128 + col] = acc[i][j][1];
      lout[(orow + 2) * 128 + col] = acc[i][j][2];
      lout[(orow + 3) * 128 + col] = acc[i][j][3];
    }
  }
  __syncthreads();
#pragma unroll
  for (int t = 0; t < 16; ++t) {
    const int idx = t * 256 + tid;        // 4096 float4s = 128 rows x 32 f4/row
    const int orow = idx >> 5;
    const int c4 = idx & 31;
    float4 v = ((const float4*)lout)[idx];
    const int o = o0 + orow;
    const float bv = bias[o];
    v.x += bv; v.y += bv; v.z += bv; v.w += bv;
    const int p = p0 + c4 * 4;
    const int bidx = p / HWN;             // 3136 % 4 == 0 -> float4 never straddles b
    const int hw = p - bidx * HWN;
    *(float4*)(out + (size_t)bidx * ON * HWN + (size_t)o * HWN + hw) = v;
  }
}

extern "C" void kernel_launch(void* const* d_in, const int* in_sizes, int n_in,
                              void* d_out, int out_size, void* d_ws, size_t ws_size,
                              hipStream_t stream) {
  const float* x = (const float*)d_in[0];       // [16,128,56,56]
  const float* w_off = (const float*)d_in[1];   // [18,128]
  const float* b_off = (const float*)d_in[2];   // [18]
  const float* w_conv = (const float*)d_in[3];  // [512,1152]
  const float* b_conv = (const float*)d_in[4];  // [512]
  float* out = (float*)d_out;                   // [16,512,56,56] fp32

  // workspace layout (16B aligned):
  //   xt  : bf16 [B,HW,C]      12,845,056 B @ 0
  //   S   : bf16 [M,K]        115,605,504 B @ 12,845,056
  //   Wb  : bf16 [512,1152]     1,179,648 B @ 128,450,560
  //   ixy : float2 [M,F]        3,612,672 B @ 129,630,208   (total ~133.2 MB)
  char* ws = (char*)d_ws;
  unsigned short* xt = (unsigned short*)(ws);
  unsigned short* S = (unsigned short*)(ws + 12845056);
  unsigned short* Wb = (unsigned short*)(ws + 128450560);
  float2* ixy = (float2*)(ws + 129630208);

  k_transpose<<<dim3(98, 4, 16), 256, 0, stream>>>(x, xt);
  k_wconv<<<dim3(576), 256, 0, stream>>>((const float4*)w_conv, (ushort4*)Wb);
  k_offsets<<<dim3(196), 256, 0, stream>>>(xt, w_off, b_off, ixy);
  k_sample<<<dim3(1568, 9), 256, 0, stream>>>(xt, ixy, S);
  k_gemm<<<dim3(4, 392), 256, 0, stream>>>(Wb, S, b_conv, out);
}

// Round 5
// 253.227 us; speedup vs baseline: 1.2052x; 1.2052x over previous
//
#include <hip/hip_runtime.h>
#include <stdint.h>
#include <stddef.h>

// Problem constants
#define BN 16
#define CN 128
#define HN 56
#define WN 56
#define HWN 3136            // H*W
#define FN 9                // K*K deformation taps
#define DN 18               // 2*F offset channels
#define ON 512              // OUT
#define KN 1152             // F*C  (GEMM K)
#define MN 50176            // B*H*W (GEMM M)

typedef __bf16 bf16x8 __attribute__((ext_vector_type(8)));
typedef float f32x4 __attribute__((ext_vector_type(4)));

__device__ __forceinline__ unsigned short f2bf(float f) {
  unsigned int u = __builtin_bit_cast(unsigned int, f);
  u += 0x7fffu + ((u >> 16) & 1u);   // round-to-nearest-even
  return (unsigned short)(u >> 16);
}

__device__ __forceinline__ void gload_lds16(const void* g, void* l) {
  __builtin_amdgcn_global_load_lds(
      (const __attribute__((address_space(1))) unsigned int*)g,
      (__attribute__((address_space(3))) unsigned int*)l, 16, 0, 0);
}

// ---------------- Phase 0a: x fp32 [B,C,HW] -> xt bf16 [B,HW,C] ----------------
__global__ void k_transpose(const float* __restrict__ x, unsigned short* __restrict__ xt) {
  __shared__ float tile[32][33];
  const int b = blockIdx.z;
  const int hw0 = blockIdx.x * 32;   // 3136/32 = 98 exact
  const int c0 = blockIdx.y * 32;    // 128/32 = 4 exact
  const int tx = threadIdx.x & 31;
  const int ty = threadIdx.x >> 5;   // 0..7
  const float* xb = x + (size_t)b * CN * HWN;
  unsigned short* xtb = xt + (size_t)b * HWN * CN;
#pragma unroll
  for (int r = 0; r < 4; ++r)
    tile[ty + r * 8][tx] = xb[(size_t)(c0 + ty + r * 8) * HWN + hw0 + tx];
  __syncthreads();
#pragma unroll
  for (int r = 0; r < 4; ++r)
    xtb[(size_t)(hw0 + ty + r * 8) * CN + c0 + tx] = f2bf(tile[tx][ty + r * 8]);
}

// ---------------- Phase 0b: w_conv fp32 -> bf16 ----------------
__global__ void k_wconv(const float4* __restrict__ w, ushort4* __restrict__ wb) {
  const int i = blockIdx.x * 256 + threadIdx.x;  // 512*1152/4 = 147456 exact
  float4 v = w[i];
  ushort4 o;
  o.x = f2bf(v.x); o.y = f2bf(v.y); o.z = f2bf(v.z); o.w = f2bf(v.w);
  wb[i] = o;
}

// ---------------- Phase 1: per-pixel offset conv -> (ix,iy) per tap ------------
// w_off staged in LDS; uniform-address float4 reads -> guaranteed broadcast.
__global__ void k_offsets(const unsigned short* __restrict__ xt, const float* __restrict__ w_off,
                          const float* __restrict__ b_off, float2* __restrict__ ixy) {
  __shared__ float lwoff[DN * CN];
  __shared__ float lboff[DN];
  for (int i = threadIdx.x; i < DN * CN; i += 256) lwoff[i] = w_off[i];
  if (threadIdx.x < DN) lboff[threadIdx.x] = b_off[threadIdx.x];
  __syncthreads();

  const int m = blockIdx.x * 256 + threadIdx.x;  // 50176 = 196*256 exact
  const int b = m / HWN;
  const int hw = m - b * HWN;
  const int h = hw / WN;
  const int w = hw - h * WN;
  const unsigned short* xp = xt + (size_t)m * CN;
  float acc[DN];
#pragma unroll
  for (int d = 0; d < DN; ++d) acc[d] = lboff[d];
  for (int c = 0; c < CN; c += 8) {
    bf16x8 xv = *(const bf16x8*)(xp + c);
    float xf[8];
#pragma unroll
    for (int q = 0; q < 8; ++q) xf[q] = (float)xv[q];
#pragma unroll
    for (int d = 0; d < DN; ++d) {
      float4 w0 = *(const float4*)(lwoff + d * CN + c);      // uniform -> broadcast
      float4 w1 = *(const float4*)(lwoff + d * CN + c + 4);
      acc[d] += xf[0] * w0.x + xf[1] * w0.y + xf[2] * w0.z + xf[3] * w0.w
              + xf[4] * w1.x + xf[5] * w1.y + xf[6] * w1.z + xf[7] * w1.w;
    }
  }
  const float scale = 2.0f / 56.0f;
  const float bx = (2.0f * w + 1.0f) / (float)WN - 1.0f;
  const float by = (2.0f * h + 1.0f) / (float)HN - 1.0f;
#pragma unroll
  for (int f = 0; f < FN; ++f) {
    float gx = bx + acc[2 * f] * scale;
    float gy = by + acc[2 * f + 1] * scale;
    float ixv = ((gx + 1.0f) * (float)WN - 1.0f) * 0.5f;
    float iyv = ((gy + 1.0f) * (float)HN - 1.0f) * 0.5f;
    ixy[(size_t)m * FN + f] = make_float2(ixv, iyv);
  }
}

// ---------------- Phase 2: bilinear sample (bf16 in) -> S bf16 [M, K] ----------
// mf-major thread order: all 9 taps of a pixel in the same block -> corner reads
// overlap in L1/L2 (measured: tap-split grid cost ~30 us).
__global__ void k_sample(const unsigned short* __restrict__ xt, const float2* __restrict__ ixy,
                         unsigned short* __restrict__ S) {
  const int g = blockIdx.x * 256 + threadIdx.x;  // 50176*9*8 = 14112*256 exact
  const int cc = g & 7;           // 16-channel chunk
  const int mf = g >> 3;          // m*9 + f
  const int m = mf / FN;
  const int f = mf - m * FN;
  const int b = m / HWN;

  const float2 p = ixy[mf];
  const float ix = p.x, iy = p.y;
  const float x0f = floorf(ix), y0f = floorf(iy);
  const float wx1 = ix - x0f, wy1 = iy - y0f;
  const float wx0 = 1.0f - wx1, wy0 = 1.0f - wy1;
  const int x0 = (int)x0f, y0 = (int)y0f;
  const int x1 = x0 + 1, y1 = y0 + 1;
  const bool vx0 = (x0 >= 0) & (x0 < WN), vx1 = (x1 >= 0) & (x1 < WN);
  const bool vy0 = (y0 >= 0) & (y0 < HN), vy1 = (y1 >= 0) & (y1 < HN);
  const float w00 = wy0 * wx0 * ((vy0 & vx0) ? 1.0f : 0.0f);
  const float w01 = wy0 * wx1 * ((vy0 & vx1) ? 1.0f : 0.0f);
  const float w10 = wy1 * wx0 * ((vy1 & vx0) ? 1.0f : 0.0f);
  const float w11 = wy1 * wx1 * ((vy1 & vx1) ? 1.0f : 0.0f);
  const int x0c = min(max(x0, 0), WN - 1), x1c = min(max(x1, 0), WN - 1);
  const int y0c = min(max(y0, 0), HN - 1), y1c = min(max(y1, 0), HN - 1);

  const unsigned short* bp = xt + (size_t)b * HWN * CN + cc * 16;
  const bf16x8* p00 = (const bf16x8*)(bp + (size_t)(y0c * WN + x0c) * CN);
  const bf16x8* p01 = (const bf16x8*)(bp + (size_t)(y0c * WN + x1c) * CN);
  const bf16x8* p10 = (const bf16x8*)(bp + (size_t)(y1c * WN + x0c) * CN);
  const bf16x8* p11 = (const bf16x8*)(bp + (size_t)(y1c * WN + x1c) * CN);
  bf16x8 a0 = p00[0], a1 = p00[1];
  bf16x8 b0 = p01[0], b1 = p01[1];
  bf16x8 c0 = p10[0], c1 = p10[1];
  bf16x8 d0 = p11[0], d1 = p11[1];

  unsigned short ov[16];
#pragma unroll
  for (int q = 0; q < 8; ++q) {
    float lo = w00 * (float)a0[q] + w01 * (float)b0[q] + w10 * (float)c0[q] + w11 * (float)d0[q];
    float hi = w00 * (float)a1[q] + w01 * (float)b1[q] + w10 * (float)c1[q] + w11 * (float)d1[q];
    ov[q] = f2bf(lo);
    ov[q + 8] = f2bf(hi);
  }
  uint4* dst = (uint4*)(S + (size_t)m * KN + f * CN + cc * 16);
  dst[0] = *(const uint4*)(ov);
  dst[1] = *(const uint4*)(ov + 8);
}

// ---------------- Phase 3: GEMM  out[o,m] = sum_k Wb[o,k]*S[m,k] + bias[o] ------
// 128x128 tile, BK=64, XOR-swizzled LDS, single-buffer (measured best R3),
// XCD-aware 1-D grid: the 4 o-tiles of one p-tile land on the SAME XCD
// (bids {32g+s, 32g+8+s, 32g+16+s, 32g+24+s} are all ≡ s mod 8) -> shared S in L2.
__global__ __launch_bounds__(256) void k_gemm(const unsigned short* __restrict__ Wb,
                                              const unsigned short* __restrict__ S,
                                              const float* __restrict__ bias,
                                              float* __restrict__ out) {
  __shared__ __align__(16) char smem[32768];
  unsigned short* lw = (unsigned short*)smem;            // 16 KB: W tile [128 o][64 k]
  unsigned short* ls = (unsigned short*)(smem + 16384);  // 16 KB: S tile [128 m][64 k]
  const int tid = threadIdx.x;
  const int wave = tid >> 6;
  const int lane = tid & 63;
  const int quad = lane >> 4;
  const int r16 = lane & 15;
  const int bid = blockIdx.x;                 // 1568 = 4 o-tiles x 392 p-tiles
  const int ot = (bid >> 3) & 3;
  const int pt = (bid & 7) + ((bid >> 5) << 3);
  const int o0 = ot * 128;
  const int p0 = pt * 128;
  const int wrow = wave >> 1;       // o-dim wave
  const int wcol = wave & 1;        // m-dim wave

  f32x4 acc[4][4];
#pragma unroll
  for (int i = 0; i < 4; ++i)
#pragma unroll
    for (int j = 0; j < 4; ++j) acc[i][j] = (f32x4){0.f, 0.f, 0.f, 0.f};

  // staging: slot s = r*256 + tid -> LDS 16B chunk s; row = s/8, chunk-in-row = s%8.
  // swizzle: LDS[row][ch] holds global chunk (ch ^ (row&7)).
  const int row0 = tid >> 3;                              // 0..31
  const int swc = (((tid & 7) ^ (row0 & 7))) * 8;         // swizzled col (shorts)
  const unsigned short* gw = Wb + (size_t)(o0 + row0) * KN + swc;
  const unsigned short* gs = S + (size_t)(p0 + row0) * KN + swc;
  unsigned short* lwd = lw + wave * 512;   // wave-uniform LDS base (shorts)
  unsigned short* lsd = ls + wave * 512;

  // reader: fragment row = wrow*64+i*16+r16 (row&7 == r16&7),
  // wanted chunk c = quad + h*4 -> LDS chunk c ^ (r16&7)
  const int rsw = r16 & 7;
  const int ch0 = (quad ^ rsw) * 8;                 // h=0 chunk offset (shorts)
  const int ch1 = ((quad ^ rsw) ^ 4) * 8;           // h=1
  const unsigned short* aw = lw + (wrow * 64 + r16) * 64;
  const unsigned short* bs = ls + (wcol * 64 + r16) * 64;

  for (int kt = 0; kt < KN / 64; ++kt) {
#pragma unroll
    for (int r = 0; r < 4; ++r) {
      gload_lds16(gw + (size_t)r * 32 * KN, lwd + r * 2048);
      gload_lds16(gs + (size_t)r * 32 * KN, lsd + r * 2048);
    }
    gw += 64; gs += 64;
    __syncthreads();
#pragma unroll
    for (int h = 0; h < 2; ++h) {
      const int ch = h ? ch1 : ch0;
      bf16x8 afr[4], bfr[4];
#pragma unroll
      for (int i = 0; i < 4; ++i) afr[i] = *(const bf16x8*)(aw + i * 16 * 64 + ch);
#pragma unroll
      for (int j = 0; j < 4; ++j) bfr[j] = *(const bf16x8*)(bs + j * 16 * 64 + ch);
#pragma unroll
      for (int i = 0; i < 4; ++i)
#pragma unroll
        for (int j = 0; j < 4; ++j)
          acc[i][j] = __builtin_amdgcn_mfma_f32_16x16x32_bf16(afr[i], bfr[j], acc[i][j], 0, 0, 0);
    }
    __syncthreads();
  }

  // Epilogue: stage 64 o-rows x 128 p-cols fp32 in smem (32 KB), write full lines.
  // C/D layout: col(m)=r16, row(o)=quad*4+reg.
  float* lout = (float*)smem;
  for (int half = 0; half < 2; ++half) {
    __syncthreads();
    if (wrow == half) {
#pragma unroll
      for (int i = 0; i < 4; ++i) {
        const int orow = i * 16 + quad * 4;
#pragma unroll
        for (int j = 0; j < 4; ++j) {
          const int col = wcol * 64 + j * 16 + r16;
          lout[(orow + 0) * 128 + col] = acc[i][j][0];
          lout[(orow + 1) * 128 + col] = acc[i][j][1];
          lout[(orow + 2) * 128 + col] = acc[i][j][2];
          lout[(orow + 3) * 128 + col] = acc[i][j][3];
        }
      }
    }
    __syncthreads();
#pragma unroll
    for (int t = 0; t < 8; ++t) {
      const int idx = t * 256 + tid;        // 2048 float4s = 64 rows x 32 f4/row
      const int orow = idx >> 5;
      const int c4 = idx & 31;
      float4 v = ((const float4*)lout)[idx];
      const int o = o0 + half * 64 + orow;
      const float bv = bias[o];
      v.x += bv; v.y += bv; v.z += bv; v.w += bv;
      const int p = p0 + c4 * 4;
      const int bidx = p / HWN;             // 3136 % 4 == 0 -> float4 never straddles b
      const int hw = p - bidx * HWN;
      *(float4*)(out + (size_t)bidx * ON * HWN + (size_t)o * HWN + hw) = v;
    }
  }
}

extern "C" void kernel_launch(void* const* d_in, const int* in_sizes, int n_in,
                              void* d_out, int out_size, void* d_ws, size_t ws_size,
                              hipStream_t stream) {
  const float* x = (const float*)d_in[0];       // [16,128,56,56]
  const float* w_off = (const float*)d_in[1];   // [18,128]
  const float* b_off = (const float*)d_in[2];   // [18]
  const float* w_conv = (const float*)d_in[3];  // [512,1152]
  const float* b_conv = (const float*)d_in[4];  // [512]
  float* out = (float*)d_out;                   // [16,512,56,56] fp32

  // workspace layout (16B aligned):
  //   xt  : bf16 [B,HW,C]      12,845,056 B @ 0
  //   S   : bf16 [M,K]        115,605,504 B @ 12,845,056
  //   Wb  : bf16 [512,1152]     1,179,648 B @ 128,450,560
  //   ixy : float2 [M,F]        3,612,672 B @ 129,630,208   (total ~133.2 MB)
  char* ws = (char*)d_ws;
  unsigned short* xt = (unsigned short*)(ws);
  unsigned short* S = (unsigned short*)(ws + 12845056);
  unsigned short* Wb = (unsigned short*)(ws + 128450560);
  float2* ixy = (float2*)(ws + 129630208);

  k_transpose<<<dim3(98, 4, 16), 256, 0, stream>>>(x, xt);
  k_wconv<<<dim3(576), 256, 0, stream>>>((const float4*)w_conv, (ushort4*)Wb);
  k_offsets<<<dim3(196), 256, 0, stream>>>(xt, w_off, b_off, ixy);
  k_sample<<<dim3(14112), 256, 0, stream>>>(xt, ixy, S);
  k_gemm<<<dim3(1568), 256, 0, stream>>>(Wb, S, b_conv, out);
}